// Round 10
// baseline (290.700 us; speedup 1.0000x reference)
//
#include <hip/hip_runtime.h>

namespace {
constexpr int kBB = 64, kH = 64, kW = 64, kC = 128, kP = 64;
constexpr int kHW = kH * kW;                 // 4096
constexpr long kRows = (long)kBB * kHW;      // 262144
constexpr long kOutElems = kRows * kC;       // 33554432

constexpr int kGemmTiles = (int)(kRows / 128); // 2048 tiles of 128 rows
constexpr int kZBlocks = 512;                  // each reduces 512 z rows
constexpr int kGrid = kGemmTiles + kZBlocks;   // 2560, interleaved 4:1 by bid%5

constexpr int kSPad = 17;  // s tile row stride in f4 (16 data + 1 pad):
                           // 272 B = 68 dwords = 4 mod 32 banks -> the wave's 4
                           // rows per ds_read hit 4 disjoint bank groups.
                           // (Round 9's stride 16 = 0 mod 32 -> 4-way conflict,
                           // SQ_LDS_BANK_CONFLICT = 4.19M.)

typedef float f4 __attribute__((ext_vector_type(4)));

// Round-10 = round-9 (2-col register tiling, 1.5x fewer DS inst) + padded s
// stride to kill the 4-way s-read bank conflict. DS-pipe theory: VALU issue
// is invariant ~44 us across rounds; DS pipe ~41 us + conflicts; HBM ~37 us.
__global__ __launch_bounds__(256) void fused_kernel(const float* __restrict__ z,
                                                    const float* __restrict__ s,
                                                    const float* __restrict__ kmat,
                                                    float* __restrict__ out,
                                                    float* __restrict__ zsum,
                                                    float* __restrict__ z2) {
  __shared__ f4 k_lds[32][kC / 4];      // 16 KB — one half of k (32 p-rows)
  __shared__ f4 s_lds[128 * kSPad];     // 34 KB — padded s tile (z: red buffer)

  const int t = threadIdx.x;
  const int bid = blockIdx.x;
  const int r5 = bid % 5;

  if (r5 == 4) {
    // ================= z-reduction block: 512 rows, one batch image ==========
    const int cq = t & 31;
    const int tg = t >> 5;
    const int zi = bid / 5;                  // 0..511
    const long row0 = (long)zi * 512;
    const int b = (int)(row0 >> 12);         // 8 z-blocks per image
    const f4* z4 = reinterpret_cast<const f4*>(z + row0 * kC);

    f4 sum = (f4){0.f, 0.f, 0.f, 0.f};
    float q = 0.f;
#pragma unroll 8
    for (int i = 0; i < 64; ++i) {           // rows tg + 8*i
      const f4 v = __builtin_nontemporal_load(&z4[((long)(tg + 8 * i)) * 32 + cq]);
      sum += v;
      q += v.x * v.x + v.y * v.y + v.z * v.z + v.w * v.w;
    }

    f4* red = &s_lds[0];                     // 256 f4 = 4 KB
    float* qred = reinterpret_cast<float*>(&k_lds[0][0]);  // k_lds unused here
    red[tg * 32 + cq] = sum;
    for (int off = 32; off > 0; off >>= 1) q += __shfl_down(q, off, 64);
    if ((t & 63) == 0) qred[t >> 6] = q;
    __syncthreads();

    if (tg == 0) {
      f4 tot = red[cq];
#pragma unroll
      for (int j = 1; j < 8; ++j) tot += red[j * 32 + cq];
      atomicAdd(&zsum[b * kC + cq * 4 + 0], tot.x);
      atomicAdd(&zsum[b * kC + cq * 4 + 1], tot.y);
      atomicAdd(&zsum[b * kC + cq * 4 + 2], tot.z);
      atomicAdd(&zsum[b * kC + cq * 4 + 3], tot.w);
      if (cq == 0) atomicAdd(&z2[b], qred[0] + qred[1] + qred[2] + qred[3]);
    }
    return;
  }

  // ================= GEMM block: one 128-row tile =============================
  const int cq2 = t & 15;   // col-pair id: owns f4-cols cq2 and cq2+16
  const int tg = t >> 4;    // row-group 0..15; owns rows tg + 16*j
  const long tile = (long)(bid / 5) * 4 + r5;    // 0..2047
  const long rowbase = tile * 128;

  // stage k first half (p=0..31, 16 KB; L2-resident after first touch)
  const f4* k4g = reinterpret_cast<const f4*>(kmat);
  f4* k_flat = &k_lds[0][0];
#pragma unroll
  for (int i = 0; i < 4; ++i) k_flat[t + 256 * i] = k4g[t + 256 * i];

  // stage s tile (32 KB data, read-once -> nontemporal), padded row stride
#pragma unroll
  for (int i = 0; i < 8; ++i) {
    const int g = t + 256 * i;               // 0..2047
    const f4 v = __builtin_nontemporal_load(
        &reinterpret_cast<const f4*>(s + rowbase * kP)[g]);
    s_lds[(g >> 4) * kSPad + (g & 15)] = v;
  }

  // prefetch k second half into regs (compiler may sink it; L2-hot either way)
  f4 kpre[4];
#pragma unroll
  for (int i = 0; i < 4; ++i) kpre[i] = k4g[1024 + t + 256 * i];

  __syncthreads();  // k-half-1 + s staged

  f4 acc0[8], acc1[8];
#pragma unroll
  for (int j = 0; j < 8; ++j) {
    acc0[j] = (f4){0.f, 0.f, 0.f, 0.f};
    acc1[j] = (f4){0.f, 0.f, 0.f, 0.f};
  }

  // ---- GEMM-A: p = 0..31 ----
#pragma unroll 2
  for (int pc = 0; pc < 8; ++pc) {  // p in chunks of 4
    const f4 ka0 = k_lds[4 * pc + 0][cq2];
    const f4 ka1 = k_lds[4 * pc + 1][cq2];
    const f4 ka2 = k_lds[4 * pc + 2][cq2];
    const f4 ka3 = k_lds[4 * pc + 3][cq2];
    const f4 kb0 = k_lds[4 * pc + 0][cq2 + 16];
    const f4 kb1 = k_lds[4 * pc + 1][cq2 + 16];
    const f4 kb2 = k_lds[4 * pc + 2][cq2 + 16];
    const f4 kb3 = k_lds[4 * pc + 3][cq2 + 16];
#pragma unroll
    for (int j = 0; j < 8; ++j) {
      const f4 sv = s_lds[(tg + 16 * j) * kSPad + pc];  // 16-lane broadcast
      acc0[j].x += sv.x * ka0.x + sv.y * ka1.x + sv.z * ka2.x + sv.w * ka3.x;
      acc0[j].y += sv.x * ka0.y + sv.y * ka1.y + sv.z * ka2.y + sv.w * ka3.y;
      acc0[j].z += sv.x * ka0.z + sv.y * ka1.z + sv.z * ka2.z + sv.w * ka3.z;
      acc0[j].w += sv.x * ka0.w + sv.y * ka1.w + sv.z * ka2.w + sv.w * ka3.w;
      acc1[j].x += sv.x * kb0.x + sv.y * kb1.x + sv.z * kb2.x + sv.w * kb3.x;
      acc1[j].y += sv.x * kb0.y + sv.y * kb1.y + sv.z * kb2.y + sv.w * kb3.y;
      acc1[j].z += sv.x * kb0.z + sv.y * kb1.z + sv.z * kb2.z + sv.w * kb3.z;
      acc1[j].w += sv.x * kb0.w + sv.y * kb1.w + sv.z * kb2.w + sv.w * kb3.w;
    }
  }

  __syncthreads();  // everyone done reading k half 1
#pragma unroll
  for (int i = 0; i < 4; ++i) k_flat[t + 256 * i] = kpre[i];
  __syncthreads();  // k half 2 visible

  // ---- GEMM-B: p = 32..63 (s f4-col pc = 8..15) ----
#pragma unroll 2
  for (int pc = 8; pc < 16; ++pc) {
    const f4 ka0 = k_lds[4 * (pc - 8) + 0][cq2];
    const f4 ka1 = k_lds[4 * (pc - 8) + 1][cq2];
    const f4 ka2 = k_lds[4 * (pc - 8) + 2][cq2];
    const f4 ka3 = k_lds[4 * (pc - 8) + 3][cq2];
    const f4 kb0 = k_lds[4 * (pc - 8) + 0][cq2 + 16];
    const f4 kb1 = k_lds[4 * (pc - 8) + 1][cq2 + 16];
    const f4 kb2 = k_lds[4 * (pc - 8) + 2][cq2 + 16];
    const f4 kb3 = k_lds[4 * (pc - 8) + 3][cq2 + 16];
#pragma unroll
    for (int j = 0; j < 8; ++j) {
      const f4 sv = s_lds[(tg + 16 * j) * kSPad + pc];
      acc0[j].x += sv.x * ka0.x + sv.y * ka1.x + sv.z * ka2.x + sv.w * ka3.x;
      acc0[j].y += sv.x * ka0.y + sv.y * ka1.y + sv.z * ka2.y + sv.w * ka3.y;
      acc0[j].z += sv.x * ka0.z + sv.y * ka1.z + sv.z * ka2.z + sv.w * ka3.z;
      acc0[j].w += sv.x * ka0.w + sv.y * ka1.w + sv.z * ka2.w + sv.w * ka3.w;
      acc1[j].x += sv.x * kb0.x + sv.y * kb1.x + sv.z * kb2.x + sv.w * kb3.x;
      acc1[j].y += sv.x * kb0.y + sv.y * kb1.y + sv.z * kb2.y + sv.w * kb3.y;
      acc1[j].z += sv.x * kb0.z + sv.y * kb1.z + sv.z * kb2.z + sv.w * kb3.z;
      acc1[j].w += sv.x * kb0.w + sv.y * kb1.w + sv.z * kb2.w + sv.w * kb3.w;
    }
  }

  f4* out4 = reinterpret_cast<f4*>(out + rowbase * kC);
#pragma unroll
  for (int j = 0; j < 8; ++j) {
    const long r = tg + 16 * j;
    __builtin_nontemporal_store(acc0[j], &out4[r * 32 + cq2]);
    __builtin_nontemporal_store(acc1[j], &out4[r * 32 + cq2 + 16]);
  }
}

// distance[b][p] = z2[b] - 2*dot(zsum[b],k[p]) + 4096*||k[p]||^2
__global__ __launch_bounds__(256) void dist_kernel(const float* __restrict__ zsum,
                                                   const float* __restrict__ z2,
                                                   const float* __restrict__ kmat,
                                                   float* __restrict__ dist) {
  const int g = blockIdx.x * 256 + threadIdx.x;  // 0..4095
  const int b = g >> 6;
  const int p = g & 63;
  const f4* zs4 = reinterpret_cast<const f4*>(zsum + b * kC);
  const f4* k4 = reinterpret_cast<const f4*>(kmat + p * kC);
  float dot = 0.f, k2 = 0.f;
#pragma unroll 8
  for (int i = 0; i < kC / 4; ++i) {
    const f4 kk = k4[i];
    const f4 zz = zs4[i];
    dot += zz.x * kk.x + zz.y * kk.y + zz.z * kk.z + zz.w * kk.w;
    k2 += kk.x * kk.x + kk.y * kk.y + kk.z * kk.z + kk.w * kk.w;
  }
  dist[g] = z2[b] - 2.f * dot + (float)kHW * k2;
}

}  // namespace

extern "C" void kernel_launch(void* const* d_in, const int* in_sizes, int n_in,
                              void* d_out, int out_size, void* d_ws, size_t ws_size,
                              hipStream_t stream) {
  const float* z = (const float*)d_in[0];      // (64,64,64,128)
  const float* s = (const float*)d_in[1];      // (64,64,64,64)
  const float* kmat = (const float*)d_in[2];   // (64,1,1,128)

  float* out = (float*)d_out;                  // 33554432 floats
  float* dist = out + kOutElems;               // 4096 floats

  float* zsum = (float*)d_ws;                  // 64*128 floats
  float* z2 = zsum + kBB * kC;                 // 64 floats

  // zero the atomic accumulators (ws is poisoned 0xAA each call)
  (void)hipMemsetAsync(d_ws, 0, (size_t)(kBB * kC + kBB) * sizeof(float), stream);

  fused_kernel<<<kGrid, 256, 0, stream>>>(z, s, kmat, out, zsum, z2);
  dist_kernel<<<16, 256, 0, stream>>>(zsum, z2, kmat, dist);
}

// Round 11
// 288.531 us; speedup vs baseline: 1.0075x; 1.0075x over previous
//
#include <hip/hip_runtime.h>

namespace {
constexpr int kBB = 64, kH = 64, kW = 64, kC = 128, kP = 64;
constexpr int kHW = kH * kW;                 // 4096
constexpr long kRows = (long)kBB * kHW;      // 262144
constexpr long kOutElems = kRows * kC;       // 33554432

constexpr int kGemmTiles = (int)(kRows / 128); // 2048 blocks, 128 rows each
constexpr int kZBlocks = 512;                  // each reduces 512 z rows
constexpr int kGrid = kGemmTiles + kZBlocks;   // 2560, interleaved 4:1 by bid%5

typedef float f4 __attribute__((ext_vector_type(4)));
typedef float f32x4 __attribute__((ext_vector_type(4)));
typedef unsigned int u32x4 __attribute__((ext_vector_type(4)));
typedef __bf16 bf16x8 __attribute__((ext_vector_type(8)));

// hi/lo bf16 split: v = hi + lo + O(2^-16 |v|). hi = truncate-to-bf16(v),
// lo = truncate-to-bf16(v - hi). Products use hh + lh + hl (drop ll).
__device__ __forceinline__ void split1(float v, unsigned& h, unsigned& l) {
  const unsigned b = __float_as_uint(v);
  const unsigned hb = b & 0xFFFF0000u;
  h = hb >> 16;
  const float r = v - __uint_as_float(hb);
  l = __float_as_uint(r) >> 16;
}

// 8 f32 (v0,v1) -> hi/lo bf16x8 fragments (element j = input j).
__device__ __forceinline__ void split8(const f4 v0, const f4 v1,
                                       bf16x8& hi, bf16x8& lo) {
  u32x4 uh, ul;
#pragma unroll
  for (int d = 0; d < 4; ++d) {
    const float e0 = (d < 2) ? v0[2 * d] : v1[2 * d - 4];
    const float e1 = (d < 2) ? v0[2 * d + 1] : v1[2 * d - 3];
    const unsigned b0 = __float_as_uint(e0), b1 = __float_as_uint(e1);
    const unsigned h0 = b0 & 0xFFFF0000u, h1 = b1 & 0xFFFF0000u;
    const float r0 = e0 - __uint_as_float(h0);
    const float r1 = e1 - __uint_as_float(h1);
    uh[d] = (h0 >> 16) | h1;
    ul[d] = (__float_as_uint(r0) >> 16) | (__float_as_uint(r1) & 0xFFFF0000u);
  }
  hi = __builtin_bit_cast(bf16x8, uh);
  lo = __builtin_bit_cast(bf16x8, ul);
}

// Round-11: the VALU-FMA GEMM was issue-bound (wall == VALU 44us + DS 41us in
// every structure, rounds 5-10). Move the GEMM to MFMA (mfma_f32_16x16x32_bf16,
// hi/lo split, 3 terms): MFMA ~6us, DS ~10us, VALU ~8us -> memory-bound.
// Layouts (m89/m91 HW-verified): A lane l holds row (l&15), 8 k-elems;
// B lane l holds col (l&15) (fed from k^T), 8 k-elems (same k scheme as A,
// so any internal k-permutation cancels); D col=l&15, row=(l>>4)*4+reg.
__global__ __launch_bounds__(256) void fused_kernel(const float* __restrict__ z,
                                                    const float* __restrict__ s,
                                                    const float* __restrict__ kmat,
                                                    float* __restrict__ out,
                                                    float* __restrict__ zsum,
                                                    float* __restrict__ z2) {
  // b-fragments of k, hi and lo: [kc][nb][lane] -> 16 B each. 16 KB + 16 KB.
  __shared__ u32x4 bhi[2][8][64];
  __shared__ u32x4 blo[2][8][64];

  const int t = threadIdx.x;
  const int bid = blockIdx.x;
  const int r5 = bid % 5;

  if (r5 == 4) {
    // ================= z-reduction block: 512 rows, one batch image ==========
    const int cq = t & 31;
    const int tg = t >> 5;
    const int zi = bid / 5;                  // 0..511
    const long row0 = (long)zi * 512;
    const int b = (int)(row0 >> 12);         // 8 z-blocks per image
    const f4* z4 = reinterpret_cast<const f4*>(z + row0 * kC);

    f4 sum = (f4){0.f, 0.f, 0.f, 0.f};
    float q = 0.f;
#pragma unroll 8
    for (int i = 0; i < 64; ++i) {           // rows tg + 8*i
      const f4 v = __builtin_nontemporal_load(&z4[((long)(tg + 8 * i)) * 32 + cq]);
      sum += v;
      q += v.x * v.x + v.y * v.y + v.z * v.z + v.w * v.w;
    }

    f4* red = reinterpret_cast<f4*>(&bhi[0][0][0]);       // 4 KB
    float* qred = reinterpret_cast<float*>(&blo[0][0][0]);
    red[tg * 32 + cq] = sum;
    for (int off = 32; off > 0; off >>= 1) q += __shfl_down(q, off, 64);
    if ((t & 63) == 0) qred[t >> 6] = q;
    __syncthreads();

    if (tg == 0) {
      f4 tot = red[cq];
#pragma unroll
      for (int j = 1; j < 8; ++j) tot += red[j * 32 + cq];
      atomicAdd(&zsum[b * kC + cq * 4 + 0], tot.x);
      atomicAdd(&zsum[b * kC + cq * 4 + 1], tot.y);
      atomicAdd(&zsum[b * kC + cq * 4 + 2], tot.z);
      atomicAdd(&zsum[b * kC + cq * 4 + 3], tot.w);
      if (cq == 0) atomicAdd(&z2[b], qred[0] + qred[1] + qred[2] + qred[3]);
    }
    return;
  }

  // ================= GEMM block: one 128-row tile, 4 waves x 32 rows =========
  const long tile = (long)(bid / 5) * 4 + r5;    // 0..2047
  const long tilebase = tile * 128;

  // ---- build k b-fragments in LDS from L2-hot kmat (once per block) ----
  // entry i = (kc, nb, lane): lane l needs k[kc*32 + (l>>4)*8 + j][nb*16 + (l&15)]
  for (int i = t; i < 1024; i += 256) {
    const int lane = i & 63, nb = (i >> 6) & 7, kc = i >> 9;
    const int p0 = kc * 32 + (lane >> 4) * 8;
    const int c = nb * 16 + (lane & 15);
    u32x4 uh, ul;
#pragma unroll
    for (int d = 0; d < 4; ++d) {
      unsigned h0, l0, h1, l1;
      split1(kmat[(p0 + 2 * d) * kC + c], h0, l0);
      split1(kmat[(p0 + 2 * d + 1) * kC + c], h1, l1);
      uh[d] = h0 | (h1 << 16);
      ul[d] = l0 | (l1 << 16);
    }
    bhi[kc][nb][lane] = uh;
    blo[kc][nb][lane] = ul;
  }
  __syncthreads();

  const int w = t >> 6;        // wave 0..3: rows [w*32, w*32+32)
  const int l = t & 63;
  const int fr = l & 15;       // A row / D col within 16-tile
  const int fq = l >> 4;       // k-chunk group / D row group

#pragma unroll
  for (int mt = 0; mt < 2; ++mt) {
    const long row16 = tilebase + w * 32 + mt * 16;
    // ---- A fragments: 8 consecutive s f32 per kc, nontemporal ----
    const float* srow = s + (row16 + fr) * (long)kP + fq * 8;
    const f4 a0 = __builtin_nontemporal_load(reinterpret_cast<const f4*>(srow));
    const f4 a1 = __builtin_nontemporal_load(reinterpret_cast<const f4*>(srow + 4));
    const f4 a2 = __builtin_nontemporal_load(reinterpret_cast<const f4*>(srow + 32));
    const f4 a3 = __builtin_nontemporal_load(reinterpret_cast<const f4*>(srow + 36));
    bf16x8 ah0, al0, ah1, al1;
    split8(a0, a1, ah0, al0);   // kc = 0 (p 0..31 slice for this lane)
    split8(a2, a3, ah1, al1);   // kc = 1

    float* obase = out + (row16 + fq * 4) * (long)kC + fr;
#pragma unroll
    for (int nb = 0; nb < 8; ++nb) {
      const bf16x8 bh0 = __builtin_bit_cast(bf16x8, bhi[0][nb][l]);
      const bf16x8 bh1 = __builtin_bit_cast(bf16x8, bhi[1][nb][l]);
      const bf16x8 bl0 = __builtin_bit_cast(bf16x8, blo[0][nb][l]);
      const bf16x8 bl1 = __builtin_bit_cast(bf16x8, blo[1][nb][l]);
      f32x4 acc = {0.f, 0.f, 0.f, 0.f};
      acc = __builtin_amdgcn_mfma_f32_16x16x32_bf16(ah0, bh0, acc, 0, 0, 0);
      acc = __builtin_amdgcn_mfma_f32_16x16x32_bf16(ah1, bh1, acc, 0, 0, 0);
      acc = __builtin_amdgcn_mfma_f32_16x16x32_bf16(al0, bh0, acc, 0, 0, 0);
      acc = __builtin_amdgcn_mfma_f32_16x16x32_bf16(al1, bh1, acc, 0, 0, 0);
      acc = __builtin_amdgcn_mfma_f32_16x16x32_bf16(ah0, bl0, acc, 0, 0, 0);
      acc = __builtin_amdgcn_mfma_f32_16x16x32_bf16(ah1, bl1, acc, 0, 0, 0);
      // D: lane l -> rows row16 + fq*4 + j, col nb*16 + fr
#pragma unroll
      for (int j = 0; j < 4; ++j)
        __builtin_nontemporal_store(acc[j], obase + nb * 16 + (long)j * kC);
    }
  }
}

// distance[b][p] = z2[b] - 2*dot(zsum[b],k[p]) + 4096*||k[p]||^2
__global__ __launch_bounds__(256) void dist_kernel(const float* __restrict__ zsum,
                                                   const float* __restrict__ z2,
                                                   const float* __restrict__ kmat,
                                                   float* __restrict__ dist) {
  const int g = blockIdx.x * 256 + threadIdx.x;  // 0..4095
  const int b = g >> 6;
  const int p = g & 63;
  const f4* zs4 = reinterpret_cast<const f4*>(zsum + b * kC);
  const f4* k4 = reinterpret_cast<const f4*>(kmat + p * kC);
  float dot = 0.f, k2 = 0.f;
#pragma unroll 8
  for (int i = 0; i < kC / 4; ++i) {
    const f4 kk = k4[i];
    const f4 zz = zs4[i];
    dot += zz.x * kk.x + zz.y * kk.y + zz.z * kk.z + zz.w * kk.w;
    k2 += kk.x * kk.x + kk.y * kk.y + kk.z * kk.z + kk.w * kk.w;
  }
  dist[g] = z2[b] - 2.f * dot + (float)kHW * k2;
}

}  // namespace

extern "C" void kernel_launch(void* const* d_in, const int* in_sizes, int n_in,
                              void* d_out, int out_size, void* d_ws, size_t ws_size,
                              hipStream_t stream) {
  const float* z = (const float*)d_in[0];      // (64,64,64,128)
  const float* s = (const float*)d_in[1];      // (64,64,64,64)
  const float* kmat = (const float*)d_in[2];   // (64,1,1,128)

  float* out = (float*)d_out;                  // 33554432 floats
  float* dist = out + kOutElems;               // 4096 floats

  float* zsum = (float*)d_ws;                  // 64*128 floats
  float* z2 = zsum + kBB * kC;                 // 64 floats

  // zero the atomic accumulators (ws is poisoned 0xAA each call)
  (void)hipMemsetAsync(d_ws, 0, (size_t)(kBB * kC + kBB) * sizeof(float), stream);

  fused_kernel<<<kGrid, 256, 0, stream>>>(z, s, kmat, out, zsum, z2);
  dist_kernel<<<16, 256, 0, stream>>>(zsum, z2, kmat, dist);
}